// Round 2
// baseline (251.369 us; speedup 1.0000x reference)
//
#include <hip/hip_runtime.h>

// Problem constants
#define Bc 8
#define Nc 2048
#define Dc 512
#define PH 512            // P*H
#define NN 4194304        // N*N
#define NT 136            // upper-tri 128x128 tiles: 16*17/2

#define BM 128
#define BN 128
#define BK 32

typedef __attribute__((ext_vector_type(8))) short bf16x8;
typedef __attribute__((ext_vector_type(4))) float f32x4;

static __device__ __forceinline__ unsigned short f2b(float x) {
    union { float f; unsigned u; } v; v.f = x;
    unsigned r = v.u + 0x7fffu + ((v.u >> 16) & 1u);   // RNE to bf16
    return (unsigned short)(r >> 16);
}

// async global->LDS DMA, 16 bytes per lane; LDS dest = wave-uniform base + lane*16
static __device__ __forceinline__ void load16_lds(const unsigned short* g, unsigned short* l) {
    __builtin_amdgcn_global_load_lds(
        (const __attribute__((address_space(1))) void*)g,
        (__attribute__((address_space(3))) void*)l,
        16, 0, 0);
}

// ---------------------------------------------------------------------------
// prep: context fp32 -> bf16, W fp32 -> bf16, zero rsum
// ---------------------------------------------------------------------------
__global__ __launch_bounds__(256) void prep_kernel(
    const float* __restrict__ ctx, const float* __restrict__ W,
    unsigned short* __restrict__ Xb, unsigned short* __restrict__ Wb,
    float* __restrict__ rsum) {
    int t = blockIdx.x * 256 + threadIdx.x;
    if (t < 2097152) {
        float4 v = ((const float4*)ctx)[t];
        ushort4 o;
        o.x = f2b(v.x); o.y = f2b(v.y); o.z = f2b(v.z); o.w = f2b(v.w);
        ((ushort4*)Xb)[t] = o;
    }
    if (t < 65536) {
        float4 v = ((const float4*)W)[t];
        ushort4 o;
        o.x = f2b(v.x); o.y = f2b(v.y); o.z = f2b(v.z); o.w = f2b(v.w);
        ((ushort4*)Wb)[t] = o;
    }
    if (t < 4096) {
        float4 z; z.x = 0.f; z.y = 0.f; z.z = 0.f; z.w = 0.f;
        ((float4*)rsum)[t] = z;
    }
}

// ===========================================================================
// 256x256 8-phase GEMM core (plain-HIP port of the verified m201 template).
//   8 waves (2M x 4N), BK=64 split as 2 k-halves of 32; LDS = 8 slots x 16KB
//   (A/B x kh0/kh1 x 2 K-tile parities) = 128 KiB dynamic.
//   Slot layout: [256 rows][32 cols bf16] row-major (64B rows), st-swizzle
//   byte ^= ((byte>>9)&1)<<5 applied to global SOURCE addr (linear LDS dest)
//   and to ds_read addr (same involution both sides).
//   Per phase: {ds_read frags | stage 1 half-slot | barrier | lgkmcnt(0) |
//   setprio(1) 16xMFMA setprio(0) | [vmcnt(6) @p4,p8] | barrier}.
//   Stage targets the slot whose last reader finished in the previous phase
//   (schedule verified phase-by-phase; vmcnt(6)=3 half-tiles x 2 loads).
//   Tail K-tiles wrap (kt&7) so per-wave vmcnt counts stay valid.
// ===========================================================================
#define SLOT_U(par, kh, isA) ((((par)*2 + (kh))*2 + (isA)) * 8192)

#define STAGE_HALF(isA_, kh_, par_, ktv) do {                                   \
    int ktm_ = (ktv) & 7;                                                       \
    const unsigned short* g_ = (isA_) ? (Aop) : (Bop);                          \
    int r0_ = (isA_) ? (arow0) : (bcol0);                                       \
    unsigned short* lb_ = &Ls[SLOT_U(par_, kh_, isA_)];                         \
    _Pragma("unroll")                                                           \
    for (int l_ = 0; l_ < 2; ++l_) {                                            \
        int d_  = (l_*512 + tid) * 16;                                          \
        int dz_ = d_ ^ (((d_>>9)&1)<<5);                                        \
        load16_lds(&g_[(size_t)(r0_ + (dz_>>6)) * 512 + ktm_*64 + (kh_)*32 + ((dz_&63)>>1)], \
                   &lb_[d_>>1]);                                                \
    }                                                                           \
} while (0)

#define PHASE(Q_, KS_, PAR_, SA_, SKH_, SPAR_, SKT_, DOVM_) do {                \
    if ((Q_) == 0) {                                                            \
        bq0 = *(const bf16x8*)&Ls[SLOT_U(PAR_, KS_, 0) + boff + 0*512];         \
        bq1 = *(const bf16x8*)&Ls[SLOT_U(PAR_, KS_, 0) + boff + 1*512];         \
        bq2 = *(const bf16x8*)&Ls[SLOT_U(PAR_, KS_, 0) + boff + 2*512];         \
        bq3 = *(const bf16x8*)&Ls[SLOT_U(PAR_, KS_, 0) + boff + 3*512];         \
    }                                                                           \
    bf16x8 a0_ = *(const bf16x8*)&Ls[SLOT_U(PAR_, KS_, 1) + aoff + ((Q_)*4+0)*512]; \
    bf16x8 a1_ = *(const bf16x8*)&Ls[SLOT_U(PAR_, KS_, 1) + aoff + ((Q_)*4+1)*512]; \
    bf16x8 a2_ = *(const bf16x8*)&Ls[SLOT_U(PAR_, KS_, 1) + aoff + ((Q_)*4+2)*512]; \
    bf16x8 a3_ = *(const bf16x8*)&Ls[SLOT_U(PAR_, KS_, 1) + aoff + ((Q_)*4+3)*512]; \
    STAGE_HALF(SA_, SKH_, SPAR_, SKT_);                                         \
    __builtin_amdgcn_s_barrier();                                               \
    asm volatile("s_waitcnt lgkmcnt(0)" ::: "memory");                          \
    __builtin_amdgcn_sched_barrier(0);                                          \
    __builtin_amdgcn_s_setprio(1);                                              \
    acc[(Q_)*4+0][0] = __builtin_amdgcn_mfma_f32_16x16x32_bf16(a0_, bq0, acc[(Q_)*4+0][0], 0, 0, 0); \
    acc[(Q_)*4+0][1] = __builtin_amdgcn_mfma_f32_16x16x32_bf16(a0_, bq1, acc[(Q_)*4+0][1], 0, 0, 0); \
    acc[(Q_)*4+0][2] = __builtin_amdgcn_mfma_f32_16x16x32_bf16(a0_, bq2, acc[(Q_)*4+0][2], 0, 0, 0); \
    acc[(Q_)*4+0][3] = __builtin_amdgcn_mfma_f32_16x16x32_bf16(a0_, bq3, acc[(Q_)*4+0][3], 0, 0, 0); \
    acc[(Q_)*4+1][0] = __builtin_amdgcn_mfma_f32_16x16x32_bf16(a1_, bq0, acc[(Q_)*4+1][0], 0, 0, 0); \
    acc[(Q_)*4+1][1] = __builtin_amdgcn_mfma_f32_16x16x32_bf16(a1_, bq1, acc[(Q_)*4+1][1], 0, 0, 0); \
    acc[(Q_)*4+1][2] = __builtin_amdgcn_mfma_f32_16x16x32_bf16(a1_, bq2, acc[(Q_)*4+1][2], 0, 0, 0); \
    acc[(Q_)*4+1][3] = __builtin_amdgcn_mfma_f32_16x16x32_bf16(a1_, bq3, acc[(Q_)*4+1][3], 0, 0, 0); \
    acc[(Q_)*4+2][0] = __builtin_amdgcn_mfma_f32_16x16x32_bf16(a2_, bq0, acc[(Q_)*4+2][0], 0, 0, 0); \
    acc[(Q_)*4+2][1] = __builtin_amdgcn_mfma_f32_16x16x32_bf16(a2_, bq1, acc[(Q_)*4+2][1], 0, 0, 0); \
    acc[(Q_)*4+2][2] = __builtin_amdgcn_mfma_f32_16x16x32_bf16(a2_, bq2, acc[(Q_)*4+2][2], 0, 0, 0); \
    acc[(Q_)*4+2][3] = __builtin_amdgcn_mfma_f32_16x16x32_bf16(a2_, bq3, acc[(Q_)*4+2][3], 0, 0, 0); \
    acc[(Q_)*4+3][0] = __builtin_amdgcn_mfma_f32_16x16x32_bf16(a3_, bq0, acc[(Q_)*4+3][0], 0, 0, 0); \
    acc[(Q_)*4+3][1] = __builtin_amdgcn_mfma_f32_16x16x32_bf16(a3_, bq1, acc[(Q_)*4+3][1], 0, 0, 0); \
    acc[(Q_)*4+3][2] = __builtin_amdgcn_mfma_f32_16x16x32_bf16(a3_, bq2, acc[(Q_)*4+3][2], 0, 0, 0); \
    acc[(Q_)*4+3][3] = __builtin_amdgcn_mfma_f32_16x16x32_bf16(a3_, bq3, acc[(Q_)*4+3][3], 0, 0, 0); \
    __builtin_amdgcn_s_setprio(0);                                              \
    if (DOVM_) { asm volatile("s_waitcnt vmcnt(6)" ::: "memory"); }             \
    __builtin_amdgcn_s_barrier();                                               \
} while (0)

// Prologue stages K0 fully + K1 {Bkh0,Akh0,Bkh1}; first in-loop p1 stages K1 Akh1.
#define GEMM256_CORE() do {                                                     \
    STAGE_HALF(0,0,0, 0); STAGE_HALF(1,0,0, 0); STAGE_HALF(0,1,0, 0); STAGE_HALF(1,1,0, 0); \
    STAGE_HALF(0,0,1, 1); STAGE_HALF(1,0,1, 1); STAGE_HALF(0,1,1, 1);           \
    asm volatile("s_waitcnt vmcnt(6)" ::: "memory");                            \
    __builtin_amdgcn_s_barrier();                                               \
    for (int it = 0; it < 4; ++it) {                                            \
        const int k1 = 2*it + 1, k2 = 2*it + 2, k3 = 2*it + 3;                  \
        PHASE(0,0,0,  1,1,1, k1, 0);                                            \
        PHASE(1,0,0,  0,0,0, k2, 0);                                            \
        PHASE(0,1,0,  1,0,0, k2, 0);                                            \
        PHASE(1,1,0,  0,1,0, k2, 1);                                            \
        PHASE(0,0,1,  1,1,0, k2, 0);                                            \
        PHASE(1,0,1,  0,0,1, k3, 0);                                            \
        PHASE(0,1,1,  1,0,1, k3, 0);                                            \
        PHASE(1,1,1,  0,1,1, k3, 1);                                            \
    }                                                                           \
} while (0)

#define GEMM256_IDS()                                                           \
    const int tid = threadIdx.x;                                                \
    const int lane = tid & 63;                                                  \
    const int wv = tid >> 6;                                                    \
    const int wm = wv >> 2, wn = wv & 3;                                        \
    const int l15 = lane & 15, q4 = lane >> 4;                                  \
    const int sxu = ((l15 >> 3) & 1) << 4;                                      \
    const int aoff = ((((wm*128 + l15) << 5) + (q4 << 3)) ^ sxu);               \
    const int boff = ((((wn*64  + l15) << 5) + (q4 << 3)) ^ sxu);

// ---------------------------------------------------------------------------
// GEMM1 (8-phase 256^2): F = relu(Xb @ Wb^T).  grid 128 x 512thr, 128KiB LDS
// ---------------------------------------------------------------------------
__global__ __launch_bounds__(512, 2) void gemm1_8ph(
    const unsigned short* __restrict__ Xb, const unsigned short* __restrict__ Wb,
    unsigned short* __restrict__ F) {
    extern __shared__ __align__(16) unsigned short Ls[];
    GEMM256_IDS();
    const int I = blockIdx.x >> 1, Jn = blockIdx.x & 1;
    const unsigned short* Aop = Xb;
    const unsigned short* Bop = Wb;
    const int arow0 = I * 256, bcol0 = Jn * 256;

    f32x4 acc[8][4] = {};
    bf16x8 bq0, bq1, bq2, bq3;
    GEMM256_CORE();

#pragma unroll
    for (int fi = 0; fi < 8; ++fi) {
        const int row = I*256 + wm*128 + fi*16 + q4*4;
#pragma unroll
        for (int ni = 0; ni < 4; ++ni) {
            const int col = Jn*256 + wn*64 + ni*16 + l15;
#pragma unroll
            for (int r = 0; r < 4; ++r)
                F[(size_t)(row + r) * PH + col] = f2b(fmaxf(acc[fi][ni][r], 0.0f));
        }
    }
}

// ---------------------------------------------------------------------------
// GEMM2 (8-phase 256^2, upper-tri): e=exp(S/16-32) -> Ework (128-tile layout,
// byte-compatible with scatter_out), col-sum atomics (+row-sum off-diag).
// grid 288 x 512thr (b = blk&7 -> XCD affinity), 128KiB LDS.
// Each wave owns exactly one 128-subtile: si=wm, sj=wn>>1.
// ---------------------------------------------------------------------------
__global__ __launch_bounds__(512, 2) void gemm2_store_8ph(
    const unsigned short* __restrict__ Fm, float* __restrict__ rsum,
    float* __restrict__ Ework) {
    extern __shared__ __align__(16) unsigned short Ls[];
    GEMM256_IDS();
    const int b = blockIdx.x & 7;
    const int T = blockIdx.x >> 3;
    int J = 0;
    while (((J + 1) * (J + 2) / 2) <= T) ++J;
    const int I = T - J * (J + 1) / 2;
    const unsigned short* Fb = Fm + (size_t)b * Nc * PH;
    const unsigned short* Aop = Fb;
    const unsigned short* Bop = Fb;
    const int arow0 = I * 256, bcol0 = J * 256;

    f32x4 acc[8][4] = {};
    bf16x8 bq0, bq1, bq2, bq3;
    GEMM256_CORE();

    // ---- epilogue: per-wave 128-subtile (si=wm, sj=wn>>1)
    const int sj = wn >> 1;
    const int i128 = 2*I + wm, j128 = 2*J + sj;
    if (!(I == J && wm == 1 && sj == 0)) {       // skip duplicated lower quadrant
        const int idx128 = j128 * (j128 + 1) / 2 + i128;
        float* Et = Ework + (size_t)(b * NT + idx128) * 16384;
        const int colb = (wn & 1) * 64;

        float csum[4] = {0.f, 0.f, 0.f, 0.f};
        float rsm[8][4];
#pragma unroll
        for (int fi = 0; fi < 8; ++fi)
#pragma unroll
            for (int r = 0; r < 4; ++r) rsm[fi][r] = 0.f;

#pragma unroll
        for (int fi = 0; fi < 8; ++fi) {
#pragma unroll
            for (int ni = 0; ni < 4; ++ni) {
#pragma unroll
                for (int r = 0; r < 4; ++r) {
                    float e = __expf(acc[fi][ni][r] * 0.0625f - 32.0f);
                    Et[(fi*16 + q4*4 + r) * 128 + colb + ni*16 + l15] = e;
                    csum[ni] += e;
                    rsm[fi][r] += e;
                }
            }
        }
#pragma unroll
        for (int ni = 0; ni < 4; ++ni) {
            float s = csum[ni];
            s += __shfl_xor(s, 16);
            s += __shfl_xor(s, 32);
            if (q4 == 0)
                atomicAdd(&rsum[b*Nc + J*256 + wn*64 + ni*16 + l15], s);
        }
        if (i128 != j128) {
#pragma unroll
            for (int fi = 0; fi < 8; ++fi) {
#pragma unroll
                for (int r = 0; r < 4; ++r) {
                    float s = rsm[fi][r];
                    s += __shfl_xor(s, 1);
                    s += __shfl_xor(s, 2);
                    s += __shfl_xor(s, 4);
                    s += __shfl_xor(s, 8);
                    if (l15 == 0)
                        atomicAdd(&rsum[b*Nc + I*256 + wm*128 + fi*16 + q4*4 + r], s);
                }
            }
        }
    }
}

// ---------------------------------------------------------------------------
// invr[b,m] = mask[b,m] / rsum[b,m]
// ---------------------------------------------------------------------------
__global__ __launch_bounds__(256) void invr_kernel(
    const float* __restrict__ rsum, const int* __restrict__ mask,
    float* __restrict__ invr) {
    int t = blockIdx.x * 256 + threadIdx.x;
    if (t < Bc * Nc) invr[t] = (float)mask[t] / rsum[t];
}

// ---------------------------------------------------------------------------
// scatter: pure memory-bound. Per upper-tri 128-tile: read 64 KB fp32 e-tile
// coalesced, write original orientation directly, write mirror (i != j) via
// padded LDS transpose. grid 1088, block 256.  (verified in R1 — unchanged)
// ---------------------------------------------------------------------------
__global__ __launch_bounds__(256) void scatter_out(
    const float* __restrict__ Ework, const float* __restrict__ invr,
    const int* __restrict__ mask, float* __restrict__ out) {
    __shared__ float Ts[32 * 132];
    const int tid = threadIdx.x;
    const int b = blockIdx.x & 7;
    const int idx = blockIdx.x >> 3;

    int j = 0;
    while (((j + 1) * (j + 2) / 2) <= idx) ++j;
    int i = idx - j * (j + 1) / 2;
    const int row0 = i * BM;
    const int col0 = j * BN;

    const float* Et   = Ework + (size_t)(b * NT + idx) * 16384;
    const float* invb = invr + b * Nc;
    const int*   mb   = mask + b * Nc;
    float* outb = out + (size_t)b * NN;

    const int cl = tid >> 3, f0 = tid & 7;
    const int mc = tid >> 1, h  = tid & 1;

    for (int ci = 0; ci < 4; ++ci) {
        if (ci) __syncthreads();
        const int r = ci * 32 + cl;
        const int n = row0 + r;
        const float mrow = (float)mb[n];
#pragma unroll
        for (int g = 0; g < 4; ++g) {
            int f = f0 + 8 * g;
            float4 ev = *(const float4*)&Et[r * 128 + 4 * f];
            *(float4*)&Ts[cl * 132 + 4 * f] = ev;
            float4 iv = *(const float4*)&invb[col0 + 4 * f];
            float4 o;
            o.x = ev.x * iv.x * mrow;
            o.y = ev.y * iv.y * mrow;
            o.z = ev.z * iv.z * mrow;
            o.w = ev.w * iv.w * mrow;
            *(float4*)&outb[(size_t)n * Nc + col0 + 4 * f] = o;
        }
        if (i == j) continue;
        __syncthreads();
        const int a = col0 + mc;
        const float mcol = (float)mb[a];
        const int nb0 = row0 + ci * 32 + 16 * h;
#pragma unroll
        for (int u = 0; u < 4; ++u) {
            float4 iv = *(const float4*)&invb[nb0 + 4 * u];
            float4 o;
            o.x = Ts[(16 * h + 4 * u + 0) * 132 + mc] * iv.x * mcol;
            o.y = Ts[(16 * h + 4 * u + 1) * 132 + mc] * iv.y * mcol;
            o.z = Ts[(16 * h + 4 * u + 2) * 132 + mc] * iv.z * mcol;
            o.w = Ts[(16 * h + 4 * u + 3) * 132 + mc] * iv.w * mcol;
            *(float4*)&outb[(size_t)a * Nc + nb0 + 4 * u] = o;
        }
    }
}

// ---------------------------------------------------------------------------
// FALLBACK kernels (small workspace): original 128^2 recompute path, verbatim.
// ---------------------------------------------------------------------------
__global__ __launch_bounds__(256) void gemm1_relu(
    const unsigned short* __restrict__ Xb, const unsigned short* __restrict__ Wb,
    unsigned short* __restrict__ F) {
    __shared__ unsigned short As[BM * BK];
    __shared__ unsigned short Bs[BN * BK];
    const int tid = threadIdx.x;
    const int lane = tid & 63;
    const int wave = tid >> 6;
    const int wm = wave >> 1, wn = wave & 1;
    const int row0 = blockIdx.y * BM;
    const int col0 = blockIdx.x * BN;

    f32x4 acc[4][4] = {};

    for (int k0 = 0; k0 < Dc; k0 += BK) {
#pragma unroll
        for (int j = 0; j < 2; ++j) {
            int e = j * 256 + tid;
            int rr = e >> 2, cc = e & 3;
            load16_lds(&Xb[(size_t)(row0 + rr) * Dc + k0 + cc * 8], &As[e * 8]);
            load16_lds(&Wb[(size_t)(col0 + rr) * Dc + k0 + cc * 8], &Bs[e * 8]);
        }
        __syncthreads();

        bf16x8 af[4], bfr[4];
#pragma unroll
        for (int i = 0; i < 4; ++i) {
            af[i]  = *(const bf16x8*)&As[(wm * 64 + i * 16 + (lane & 15)) * BK + (lane >> 4) * 8];
            bfr[i] = *(const bf16x8*)&Bs[(wn * 64 + i * 16 + (lane & 15)) * BK + (lane >> 4) * 8];
        }
#pragma unroll
        for (int mi = 0; mi < 4; ++mi)
#pragma unroll
            for (int ni = 0; ni < 4; ++ni)
                acc[mi][ni] = __builtin_amdgcn_mfma_f32_16x16x32_bf16(af[mi], bfr[ni], acc[mi][ni], 0, 0, 0);
        __syncthreads();
    }

#pragma unroll
    for (int mi = 0; mi < 4; ++mi) {
#pragma unroll
        for (int ni = 0; ni < 4; ++ni) {
            int col  = col0 + wn * 64 + ni * 16 + (lane & 15);
            int rowb = row0 + wm * 64 + mi * 16 + ((lane >> 4) << 2);
#pragma unroll
            for (int r = 0; r < 4; ++r) {
                float v = fmaxf(acc[mi][ni][r], 0.0f);
                F[(size_t)(rowb + r) * PH + col] = f2b(v);
            }
        }
    }
}

__global__ __launch_bounds__(256) void gemm2_rsum(
    const unsigned short* __restrict__ F, float* __restrict__ rsum) {
    __shared__ unsigned short As[BM * BK];
    __shared__ unsigned short Bs[BN * BK];
    const int tid = threadIdx.x;
    const int lane = tid & 63;
    const int wave = tid >> 6;
    const int wm = wave >> 1, wn = wave & 1;
    const int b = blockIdx.y;

    int idx = blockIdx.x;
    int j = 0;
    while (((j + 1) * (j + 2) / 2) <= idx) ++j;
    int i = idx - j * (j + 1) / 2;
    const int row0 = i * BM;
    const int col0 = j * BN;
    const unsigned short* Fb = F + (size_t)b * Nc * PH;

    f32x4 acc[4][4] = {};

    for (int k0 = 0; k0 < PH; k0 += BK) {
#pragma unroll
        for (int jj = 0; jj < 2; ++jj) {
            int e = jj * 256 + tid;
            int rr = e >> 2, cc = e & 3;
            load16_lds(&Fb[(size_t)(row0 + rr) * PH + k0 + cc * 8], &As[e * 8]);
            load16_lds(&Fb[(size_t)(col0 + rr) * PH + k0 + cc * 8], &Bs[e * 8]);
        }
        __syncthreads();

        bf16x8 af[4], bfr[4];
#pragma unroll
        for (int q = 0; q < 4; ++q) {
            af[q]  = *(const bf16x8*)&As[(wm * 64 + q * 16 + (lane & 15)) * BK + (lane >> 4) * 8];
            bfr[q] = *(const bf16x8*)&Bs[(wn * 64 + q * 16 + (lane & 15)) * BK + (lane >> 4) * 8];
        }
#pragma unroll
        for (int mi = 0; mi < 4; ++mi)
#pragma unroll
            for (int ni = 0; ni < 4; ++ni)
                acc[mi][ni] = __builtin_amdgcn_mfma_f32_16x16x32_bf16(af[mi], bfr[ni], acc[mi][ni], 0, 0, 0);
        __syncthreads();
    }

    float csum[4] = {0.f, 0.f, 0.f, 0.f};
    float rsm[4][4];
#pragma unroll
    for (int mi = 0; mi < 4; ++mi)
#pragma unroll
        for (int r = 0; r < 4; ++r) rsm[mi][r] = 0.f;

#pragma unroll
    for (int mi = 0; mi < 4; ++mi) {
#pragma unroll
        for (int ni = 0; ni < 4; ++ni) {
#pragma unroll
            for (int r = 0; r < 4; ++r) {
                float e = __expf(acc[mi][ni][r] * 0.0625f - 32.0f);
                csum[ni] += e;
                rsm[mi][r] += e;
            }
        }
    }
#pragma unroll
    for (int ni = 0; ni < 4; ++ni) {
        float s = csum[ni];
        s += __shfl_xor(s, 16);
        s += __shfl_xor(s, 32);
        if ((lane >> 4) == 0)
            atomicAdd(&rsum[b * Nc + col0 + wn * 64 + ni * 16 + lane], s);
    }
    if (i != j) {
#pragma unroll
        for (int mi = 0; mi < 4; ++mi) {
#pragma unroll
            for (int r = 0; r < 4; ++r) {
                float s = rsm[mi][r];
                s += __shfl_xor(s, 1);
                s += __shfl_xor(s, 2);
                s += __shfl_xor(s, 4);
                s += __shfl_xor(s, 8);
                if ((lane & 15) == 0)
                    atomicAdd(&rsum[b * Nc + row0 + wm * 64 + mi * 16 + ((lane >> 4) << 2) + r], s);
            }
        }
    }
}

__global__ __launch_bounds__(256) void gemm2_write_sym(
    const unsigned short* __restrict__ F, const float* __restrict__ invr,
    const int* __restrict__ mask, float* __restrict__ out) {
    __shared__ unsigned short As[BM * BK];
    __shared__ unsigned short Bs[BN * BK];
    __shared__ float Ts[32 * 132];
    const int tid = threadIdx.x;
    const int lane = tid & 63;
    const int wave = tid >> 6;
    const int wm = wave >> 1, wn = wave & 1;
    const int l15 = lane & 15, q = lane >> 4;
    const int b = blockIdx.y;

    int idx = blockIdx.x;
    int j = 0;
    while (((j + 1) * (j + 2) / 2) <= idx) ++j;
    int i = idx - j * (j + 1) / 2;
    const int row0 = i * BM;
    const int col0 = j * BN;
    const unsigned short* Fb = F + (size_t)b * Nc * PH;

    f32x4 acc[4][4] = {};

    for (int k0 = 0; k0 < PH; k0 += BK) {
#pragma unroll
        for (int jj = 0; jj < 2; ++jj) {
            int e = jj * 256 + tid;
            int rr = e >> 2, cc = e & 3;
            load16_lds(&Fb[(size_t)(row0 + rr) * PH + k0 + cc * 8], &As[e * 8]);
            load16_lds(&Fb[(size_t)(col0 + rr) * PH + k0 + cc * 8], &Bs[e * 8]);
        }
        __syncthreads();

        bf16x8 af[4], bfr[4];
#pragma unroll
        for (int qq = 0; qq < 4; ++qq) {
            af[qq]  = *(const bf16x8*)&As[(wm * 64 + qq * 16 + l15) * BK + q * 8];
            bfr[qq] = *(const bf16x8*)&Bs[(wn * 64 + qq * 16 + l15) * BK + q * 8];
        }
#pragma unroll
        for (int mi = 0; mi < 4; ++mi)
#pragma unroll
            for (int ni = 0; ni < 4; ++ni)
                acc[mi][ni] = __builtin_amdgcn_mfma_f32_16x16x32_bf16(af[mi], bfr[ni], acc[mi][ni], 0, 0, 0);
        __syncthreads();
    }

#pragma unroll
    for (int mi = 0; mi < 4; ++mi)
#pragma unroll
        for (int ni = 0; ni < 4; ++ni)
#pragma unroll
            for (int r = 0; r < 4; ++r)
                acc[mi][ni][r] = __expf(acc[mi][ni][r] * 0.0625f - 32.0f);

    float* outb = out + (size_t)b * NN;

    float iv[4];
#pragma unroll
    for (int ni = 0; ni < 4; ++ni)
        iv[ni] = invr[b * Nc + col0 + wn * 64 + ni * 16 + l15];
#pragma unroll
    for (int mi = 0; mi < 4; ++mi) {
        int rowb = row0 + wm * 64 + mi * 16 + (q << 2);
        const int4 mr4 = *(const int4*)&mask[b * Nc + rowb];
        float mr[4] = {(float)mr4.x, (float)mr4.y, (float)mr4.z, (float)mr4.w};
#pragma unroll
        for (int ni = 0; ni < 4; ++ni) {
            int col = col0 + wn * 64 + ni * 16 + l15;
#pragma unroll
            for (int r = 0; r < 4; ++r)
                outb[(size_t)(rowb + r) * Nc + col] = acc[mi][ni][r] * iv[ni] * mr[r];
        }
    }

    if (i != j) {
#pragma unroll
        for (int ci = 0; ci < 4; ++ci) {
            __syncthreads();
            if (wn == (ci >> 1)) {
#pragma unroll
                for (int ni2 = 0; ni2 < 2; ++ni2) {
                    int ni = (ci & 1) * 2 + ni2;
#pragma unroll
                    for (int mi = 0; mi < 4; ++mi) {
                        *(float4*)&Ts[(ni2 * 16 + l15) * 132 + wm * 64 + mi * 16 + (q << 2)] =
                            *(float4*)&acc[mi][ni];
                    }
                }
            }
            __syncthreads();
            int cl = tid >> 3;
            int f0 = tid & 7;
            int nn = col0 + ci * 32 + cl;
            float mrow = (float)mask[b * Nc + nn];
            float* orow = &outb[(size_t)nn * Nc + row0];
#pragma unroll
            for (int g = 0; g < 4; ++g) {
                int f = f0 + g * 8;
                float4 ev  = *(float4*)&Ts[cl * 132 + 4 * f];
                float4 iv4 = *(const float4*)&invr[b * Nc + row0 + 4 * f];
                float4 o;
                o.x = ev.x * iv4.x * mrow;
                o.y = ev.y * iv4.y * mrow;
                o.z = ev.z * iv4.z * mrow;
                o.w = ev.w * iv4.w * mrow;
                *(float4*)&orow[4 * f] = o;
            }
        }
    }
}

// ---------------------------------------------------------------------------
extern "C" void kernel_launch(void* const* d_in, const int* in_sizes, int n_in,
                              void* d_out, int out_size, void* d_ws, size_t ws_size,
                              hipStream_t stream) {
    const float* ctx  = (const float*)d_in[0];   // [8,2048,512] fp32
    const float* W    = (const float*)d_in[1];   // [16,32,512] fp32
    const int*   mask = (const int*)d_in[2];     // [8,2048] int32
    float* out = (float*)d_out;                  // [8,2048,2048] fp32

    char* ws = (char*)d_ws;

    // New-path layout: Ework(fp32, 1088 tiles * 64KB = 71303168) overlays dead Xb/Wb.
    //   [0 .. 71303168)           Ework   (Xb at 0, Wb at 16777216 live only until gemm1)
    //   [71303168 .. 88080384)    F (bf16, 16384x512)
    //   [88080384 .. 88145920)    rsum
    //   [88145920 .. 88211456)    invr
    const size_t NEED = 88211456;

    if (ws_size >= NEED) {
        float*          Ework = (float*)ws;
        unsigned short* Xb    = (unsigned short*)ws;
        unsigned short* Wb    = (unsigned short*)(ws + 16777216);
        unsigned short* F     = (unsigned short*)(ws + 71303168);
        float*          rsum  = (float*)(ws + 88080384);
        float*          invr  = (float*)(ws + 88145920);

        hipFuncSetAttribute(reinterpret_cast<const void*>(gemm1_8ph),
                            hipFuncAttributeMaxDynamicSharedMemorySize, 131072);
        hipFuncSetAttribute(reinterpret_cast<const void*>(gemm2_store_8ph),
                            hipFuncAttributeMaxDynamicSharedMemorySize, 131072);

        prep_kernel<<<8192, 256, 0, stream>>>(ctx, W, Xb, Wb, rsum);
        gemm1_8ph<<<128, 512, 131072, stream>>>(Xb, Wb, F);
        gemm2_store_8ph<<<288, 512, 131072, stream>>>(F, rsum, Ework);
        invr_kernel<<<64, 256, 0, stream>>>(rsum, mask, invr);
        scatter_out<<<1088, 256, 0, stream>>>(Ework, invr, mask, out);
    } else {
        // fallback: original recompute path (needs ~34.2 MB)
        unsigned short* Xb = (unsigned short*)ws;
        unsigned short* Wb = (unsigned short*)(ws + 16777216);
        unsigned short* F  = (unsigned short*)(ws + 16777216 + 524288);
        float* rsum        = (float*)(ws + 16777216 + 524288 + 16777216);
        float* invr        = (float*)(ws + 16777216 + 524288 + 16777216 + 65536);

        prep_kernel<<<8192, 256, 0, stream>>>(ctx, W, Xb, Wb, rsum);
        gemm1_relu<<<dim3(4, 128), 256, 0, stream>>>(Xb, Wb, F);
        gemm2_rsum<<<dim3(136, 8), 256, 0, stream>>>(F, rsum);
        invr_kernel<<<64, 256, 0, stream>>>(rsum, mask, invr);
        gemm2_write_sym<<<dim3(136, 8), 256, 0, stream>>>(F, invr, mask, out);
    }
}

// Round 4
// 246.111 us; speedup vs baseline: 1.0214x; 1.0214x over previous
//
#include <hip/hip_runtime.h>

// Problem constants
#define Bc 8
#define Nc 2048
#define Dc 512
#define PH 512            // P*H
#define NN 4194304        // N*N
#define NT 136            // upper-tri 128x128 tiles: 16*17/2

#define BM 128
#define BN 128
#define BK 32

typedef __attribute__((ext_vector_type(8))) short bf16x8;
typedef __attribute__((ext_vector_type(4))) float f32x4;

static __device__ __forceinline__ unsigned short f2b(float x) {
    union { float f; unsigned u; } v; v.f = x;
    unsigned r = v.u + 0x7fffu + ((v.u >> 16) & 1u);   // RNE to bf16
    return (unsigned short)(r >> 16);
}

static __device__ __forceinline__ unsigned short f2h(float x) {
    _Float16 h = (_Float16)x;                          // RNE f32->f16
    return __builtin_bit_cast(unsigned short, h);
}

// async global->LDS DMA, 16 bytes per lane; LDS dest = wave-uniform base + lane*16
static __device__ __forceinline__ void load16_lds(const unsigned short* g, unsigned short* l) {
    __builtin_amdgcn_global_load_lds(
        (const __attribute__((address_space(1))) void*)g,
        (__attribute__((address_space(3))) void*)l,
        16, 0, 0);
}

// ---------------------------------------------------------------------------
// prep: context fp32 -> bf16, W fp32 -> bf16, zero rsum
// ---------------------------------------------------------------------------
__global__ __launch_bounds__(256) void prep_kernel(
    const float* __restrict__ ctx, const float* __restrict__ W,
    unsigned short* __restrict__ Xb, unsigned short* __restrict__ Wb,
    float* __restrict__ rsum) {
    int t = blockIdx.x * 256 + threadIdx.x;
    if (t < 2097152) {
        float4 v = ((const float4*)ctx)[t];
        ushort4 o;
        o.x = f2b(v.x); o.y = f2b(v.y); o.z = f2b(v.z); o.w = f2b(v.w);
        ((ushort4*)Xb)[t] = o;
    }
    if (t < 65536) {
        float4 v = ((const float4*)W)[t];
        ushort4 o;
        o.x = f2b(v.x); o.y = f2b(v.y); o.z = f2b(v.z); o.w = f2b(v.w);
        ((ushort4*)Wb)[t] = o;
    }
    if (t < 4096) {
        float4 z; z.x = 0.f; z.y = 0.f; z.z = 0.f; z.w = 0.f;
        ((float4*)rsum)[t] = z;
    }
}

// ---------------------------------------------------------------------------
// GEMM1: F = relu(Xb @ Wb^T)   Xb:[16384,512] Wb:[512,512]
// grid: (4, 128), block 256
// ---------------------------------------------------------------------------
__global__ __launch_bounds__(256) void gemm1_relu(
    const unsigned short* __restrict__ Xb, const unsigned short* __restrict__ Wb,
    unsigned short* __restrict__ F) {
    __shared__ unsigned short As[BM * BK];
    __shared__ unsigned short Bs[BN * BK];
    const int tid = threadIdx.x;
    const int lane = tid & 63;
    const int wave = tid >> 6;
    const int wm = wave >> 1, wn = wave & 1;
    const int row0 = blockIdx.y * BM;
    const int col0 = blockIdx.x * BN;

    f32x4 acc[4][4] = {};

    for (int k0 = 0; k0 < Dc; k0 += BK) {
#pragma unroll
        for (int j = 0; j < 2; ++j) {
            int e = j * 256 + tid;
            int rr = e >> 2, cc = e & 3;
            load16_lds(&Xb[(size_t)(row0 + rr) * Dc + k0 + cc * 8], &As[e * 8]);
            load16_lds(&Wb[(size_t)(col0 + rr) * Dc + k0 + cc * 8], &Bs[e * 8]);
        }
        __syncthreads();

        bf16x8 af[4], bfr[4];
#pragma unroll
        for (int i = 0; i < 4; ++i) {
            af[i]  = *(const bf16x8*)&As[(wm * 64 + i * 16 + (lane & 15)) * BK + (lane >> 4) * 8];
            bfr[i] = *(const bf16x8*)&Bs[(wn * 64 + i * 16 + (lane & 15)) * BK + (lane >> 4) * 8];
        }
#pragma unroll
        for (int mi = 0; mi < 4; ++mi)
#pragma unroll
            for (int ni = 0; ni < 4; ++ni)
                acc[mi][ni] = __builtin_amdgcn_mfma_f32_16x16x32_bf16(af[mi], bfr[ni], acc[mi][ni], 0, 0, 0);
        __syncthreads();
    }

#pragma unroll
    for (int mi = 0; mi < 4; ++mi) {
#pragma unroll
        for (int ni = 0; ni < 4; ++ni) {
            int col  = col0 + wn * 64 + ni * 16 + (lane & 15);
            int rowb = row0 + wm * 64 + mi * 16 + ((lane >> 4) << 2);
#pragma unroll
            for (int r = 0; r < 4; ++r) {
                float v = fmaxf(acc[mi][ni][r], 0.0f);
                F[(size_t)(rowb + r) * PH + col] = f2b(v);
            }
        }
    }
}

// ---------------------------------------------------------------------------
// diag: h[r] = ||F_r||^2 / 32  (half of S_rr/16), pH[r] = exp(h[r]).
// one wave per row; grid 4096 x 256.
// ---------------------------------------------------------------------------
__global__ __launch_bounds__(256) void diag_kernel(
    const unsigned short* __restrict__ F, float* __restrict__ hd,
    float* __restrict__ pH) {
    const int row = blockIdx.x * 4 + (threadIdx.x >> 6);
    const int lane = threadIdx.x & 63;
    uint4 u = *(const uint4*)(F + (size_t)row * PH + lane * 8);
    float s = 0.f;
    {
        float a0 = __builtin_bit_cast(float, u.x << 16);
        float a1 = __builtin_bit_cast(float, u.x & 0xffff0000u);
        float a2 = __builtin_bit_cast(float, u.y << 16);
        float a3 = __builtin_bit_cast(float, u.y & 0xffff0000u);
        float a4 = __builtin_bit_cast(float, u.z << 16);
        float a5 = __builtin_bit_cast(float, u.z & 0xffff0000u);
        float a6 = __builtin_bit_cast(float, u.w << 16);
        float a7 = __builtin_bit_cast(float, u.w & 0xffff0000u);
        s = a0*a0 + a1*a1 + a2*a2 + a3*a3 + a4*a4 + a5*a5 + a6*a6 + a7*a7;
    }
    s += __shfl_xor(s, 1);
    s += __shfl_xor(s, 2);
    s += __shfl_xor(s, 4);
    s += __shfl_xor(s, 8);
    s += __shfl_xor(s, 16);
    s += __shfl_xor(s, 32);
    if (lane == 0) {
        float h = s * 0.03125f;        // (s/16) * 0.5
        hd[row] = h;
        pH[row] = __expf(h);
    }
}

// ---------------------------------------------------------------------------
// pass 3: tri-GEMM; e_sym = exp(S/16 - h[row] - h[col]) stored FP16 (<=1 by
// AM-GM >= Cauchy-Schwarz; diag stores exactly 1.0). rsum[m] accumulates
// e_sym * pH[row] (fp32). grid: 1088 1-D (b = blk&7 -> XCD affinity), blk 256.
// ---------------------------------------------------------------------------
__global__ __launch_bounds__(256) void gemm2_store(
    const unsigned short* __restrict__ F, const float* __restrict__ hd,
    const float* __restrict__ pH, float* __restrict__ rsum,
    unsigned short* __restrict__ Ework) {
    __shared__ unsigned short As[BM * BK];
    __shared__ unsigned short Bs[BN * BK];
    const int tid = threadIdx.x;
    const int lane = tid & 63;
    const int wave = tid >> 6;
    const int wm = wave >> 1, wn = wave & 1;
    const int l15 = lane & 15, q = lane >> 4;
    const int b = blockIdx.x & 7;          // batch -> XCD (L2 locality heuristic)
    const int idx = blockIdx.x >> 3;

    // upper-triangular tile index: idx = j*(j+1)/2 + i, i <= j
    int j = 0;
    while (((j + 1) * (j + 2) / 2) <= idx) ++j;
    int i = idx - j * (j + 1) / 2;
    const int row0 = i * BM;
    const int col0 = j * BN;
    const unsigned short* Fb = F + (size_t)b * Nc * PH;

    f32x4 acc[4][4] = {};

    for (int k0 = 0; k0 < PH; k0 += BK) {
#pragma unroll
        for (int jj = 0; jj < 2; ++jj) {
            int e = jj * 256 + tid;
            int rr = e >> 2, cc = e & 3;
            load16_lds(&Fb[(size_t)(row0 + rr) * PH + k0 + cc * 8], &As[e * 8]);
            load16_lds(&Fb[(size_t)(col0 + rr) * PH + k0 + cc * 8], &Bs[e * 8]);
        }
        __syncthreads();

        bf16x8 af[4], bfr[4];
#pragma unroll
        for (int qq = 0; qq < 4; ++qq) {
            af[qq]  = *(const bf16x8*)&As[(wm * 64 + qq * 16 + l15) * BK + q * 8];
            bfr[qq] = *(const bf16x8*)&Bs[(wn * 64 + qq * 16 + l15) * BK + q * 8];
        }
#pragma unroll
        for (int mi = 0; mi < 4; ++mi)
#pragma unroll
            for (int ni = 0; ni < 4; ++ni)
                acc[mi][ni] = __builtin_amdgcn_mfma_f32_16x16x32_bf16(af[mi], bfr[ni], acc[mi][ni], 0, 0, 0);
        __syncthreads();
    }

    // epilogue
    const float* hdb = hd + b * Nc;
    const float* pHb = pH + b * Nc;
    unsigned short* Et = Ework + (size_t)(b * NT + idx) * 16384;

    float hcol[4], phc[4];
#pragma unroll
    for (int ni = 0; ni < 4; ++ni) {
        int col = col0 + wn * 64 + ni * 16 + l15;
        hcol[ni] = hdb[col];
        phc[ni]  = pHb[col];
    }
    f32x4 hrow[4], phr[4];
#pragma unroll
    for (int mi = 0; mi < 4; ++mi) {
        int rw = row0 + wm * 64 + mi * 16 + (q << 2);
        hrow[mi] = *(const f32x4*)&hdb[rw];
        phr[mi]  = *(const f32x4*)&pHb[rw];
    }

    float csum[4] = {0.f, 0.f, 0.f, 0.f};
    float rsm[4][4];
#pragma unroll
    for (int mi = 0; mi < 4; ++mi)
#pragma unroll
        for (int r = 0; r < 4; ++r) rsm[mi][r] = 0.f;

#pragma unroll
    for (int mi = 0; mi < 4; ++mi) {
#pragma unroll
        for (int ni = 0; ni < 4; ++ni) {
#pragma unroll
            for (int r = 0; r < 4; ++r) {
                float e = __expf(acc[mi][ni][r] * 0.0625f - hcol[ni] - hrow[mi][r]);
                Et[(wm * 64 + mi * 16 + (q << 2) + r) * 128 + wn * 64 + ni * 16 + l15] = f2h(e);
                csum[ni] += e * phr[mi][r];     // weight pH[row] for column-sum
                rsm[mi][r] += e * phc[ni];      // weight pH[col] for mirrored row-sum
            }
        }
    }
#pragma unroll
    for (int ni = 0; ni < 4; ++ni) {
        float s = csum[ni];
        s += __shfl_xor(s, 16);
        s += __shfl_xor(s, 32);
        if ((lane >> 4) == 0)
            atomicAdd(&rsum[b * Nc + col0 + wn * 64 + ni * 16 + lane], s);
    }
    if (i != j) {
#pragma unroll
        for (int mi = 0; mi < 4; ++mi) {
#pragma unroll
            for (int r = 0; r < 4; ++r) {
                float s = rsm[mi][r];
                s += __shfl_xor(s, 1);
                s += __shfl_xor(s, 2);
                s += __shfl_xor(s, 4);
                s += __shfl_xor(s, 8);
                if ((lane & 15) == 0)
                    atomicAdd(&rsum[b * Nc + row0 + wm * 64 + mi * 16 + ((lane >> 4) << 2) + r], s);
            }
        }
    }
}

// ---------------------------------------------------------------------------
// invr[b,m] = mask[b,m] / rsum[b,m]
// ---------------------------------------------------------------------------
__global__ __launch_bounds__(256) void invr_kernel(
    const float* __restrict__ rsum, const int* __restrict__ mask,
    float* __restrict__ invr) {
    int t = blockIdx.x * 256 + threadIdx.x;
    if (t < Bc * Nc) invr[t] = (float)mask[t] / rsum[t];
}

// ---------------------------------------------------------------------------
// pass 5: pure memory-bound scatter, fp16 e_sym tiles.
// out[n,m] = e_sym[n,m] * pH[n] * mask[n] * invr[m]; e_sym symmetric, so the
// mirror phase uses the identical form with (n,m) from the transposed read.
// grid 1088, block 256.
// ---------------------------------------------------------------------------
__global__ __launch_bounds__(256) void scatter_out(
    const unsigned short* __restrict__ Ework, const float* __restrict__ invr,
    const float* __restrict__ pH, const int* __restrict__ mask,
    float* __restrict__ out) {
    __shared__ float Ts[32 * 132];
    const int tid = threadIdx.x;
    const int b = blockIdx.x & 7;
    const int idx = blockIdx.x >> 3;

    int j = 0;
    while (((j + 1) * (j + 2) / 2) <= idx) ++j;
    int i = idx - j * (j + 1) / 2;
    const int row0 = i * BM;   // n-range of stored tile rows
    const int col0 = j * BN;   // m-range of stored tile cols

    const unsigned short* Et = Ework + (size_t)(b * NT + idx) * 16384;
    const float* invb = invr + b * Nc;
    const float* pHb  = pH + b * Nc;
    const int*   mb   = mask + b * Nc;
    float* outb = out + (size_t)b * NN;

    const int cl = tid >> 3, f0 = tid & 7;   // phase A: 32 rows x 8 lanes/row
    const int mc = tid >> 1, h  = tid & 1;   // phase B: 128 mirror-rows x 2 halves

    for (int ci = 0; ci < 4; ++ci) {         // 32-row chunks of the 128x128 tile
        if (ci) __syncthreads();             // Ts reuse across chunks
        const int r = ci * 32 + cl;
        const int n = row0 + r;
        const float mrow = (float)mb[n] * pHb[n];
#pragma unroll
        for (int g = 0; g < 2; ++g) {        // 2 x 8 halves (16B load) per lane
            const int c0 = 64 * g + 8 * f0;
            union { int4 iv; _Float16 hv[8]; } u;
            u.iv = *(const int4*)&Et[r * 128 + c0];
            float ev[8];
#pragma unroll
            for (int k = 0; k < 8; ++k) ev[k] = (float)u.hv[k];
            *(float4*)&Ts[cl * 132 + c0]     = *(float4*)&ev[0];
            *(float4*)&Ts[cl * 132 + c0 + 4] = *(float4*)&ev[4];
            float4 iv0 = *(const float4*)&invb[col0 + c0];
            float4 iv1 = *(const float4*)&invb[col0 + c0 + 4];
            float4 o0, o1;
            o0.x = ev[0] * iv0.x * mrow;
            o0.y = ev[1] * iv0.y * mrow;
            o0.z = ev[2] * iv0.z * mrow;
            o0.w = ev[3] * iv0.w * mrow;
            o1.x = ev[4] * iv1.x * mrow;
            o1.y = ev[5] * iv1.y * mrow;
            o1.z = ev[6] * iv1.z * mrow;
            o1.w = ev[7] * iv1.w * mrow;
            *(float4*)&outb[(size_t)n * Nc + col0 + c0]     = o0;
            *(float4*)&outb[(size_t)n * Nc + col0 + c0 + 4] = o1;
        }
        if (i == j) continue;                // diag tile: no mirror (uniform branch)
        __syncthreads();
        const int a = col0 + mc;             // mirror out-row n
        const float mrowB = (float)mb[a] * pHb[a];
        const int nb0 = row0 + ci * 32 + 16 * h;
#pragma unroll
        for (int u = 0; u < 4; ++u) {
            float4 iv = *(const float4*)&invb[nb0 + 4 * u];
            float4 o;
            o.x = Ts[(16 * h + 4 * u + 0) * 132 + mc] * iv.x * mrowB;
            o.y = Ts[(16 * h + 4 * u + 1) * 132 + mc] * iv.y * mrowB;
            o.z = Ts[(16 * h + 4 * u + 2) * 132 + mc] * iv.z * mrowB;
            o.w = Ts[(16 * h + 4 * u + 3) * 132 + mc] * iv.w * mrowB;
            *(float4*)&outb[(size_t)a * Nc + nb0 + 4 * u] = o;
        }
    }
}

// ---------------------------------------------------------------------------
// FALLBACK (small workspace): original recompute path, verbatim (fp32,
// self-consistent with constant offset 32).
// ---------------------------------------------------------------------------
__global__ __launch_bounds__(256) void gemm2_rsum(
    const unsigned short* __restrict__ F, float* __restrict__ rsum) {
    __shared__ unsigned short As[BM * BK];
    __shared__ unsigned short Bs[BN * BK];
    const int tid = threadIdx.x;
    const int lane = tid & 63;
    const int wave = tid >> 6;
    const int wm = wave >> 1, wn = wave & 1;
    const int b = blockIdx.y;

    int idx = blockIdx.x;
    int j = 0;
    while (((j + 1) * (j + 2) / 2) <= idx) ++j;
    int i = idx - j * (j + 1) / 2;
    const int row0 = i * BM;
    const int col0 = j * BN;
    const unsigned short* Fb = F + (size_t)b * Nc * PH;

    f32x4 acc[4][4] = {};

    for (int k0 = 0; k0 < PH; k0 += BK) {
#pragma unroll
        for (int jj = 0; jj < 2; ++jj) {
            int e = jj * 256 + tid;
            int rr = e >> 2, cc = e & 3;
            load16_lds(&Fb[(size_t)(row0 + rr) * PH + k0 + cc * 8], &As[e * 8]);
            load16_lds(&Fb[(size_t)(col0 + rr) * PH + k0 + cc * 8], &Bs[e * 8]);
        }
        __syncthreads();

        bf16x8 af[4], bfr[4];
#pragma unroll
        for (int q = 0; q < 4; ++q) {
            af[q]  = *(const bf16x8*)&As[(wm * 64 + q * 16 + (lane & 15)) * BK + (lane >> 4) * 8];
            bfr[q] = *(const bf16x8*)&Bs[(wn * 64 + q * 16 + (lane & 15)) * BK + (lane >> 4) * 8];
        }
#pragma unroll
        for (int mi = 0; mi < 4; ++mi)
#pragma unroll
            for (int ni = 0; ni < 4; ++ni)
                acc[mi][ni] = __builtin_amdgcn_mfma_f32_16x16x32_bf16(af[mi], bfr[ni], acc[mi][ni], 0, 0, 0);
        __syncthreads();
    }

    float csum[4] = {0.f, 0.f, 0.f, 0.f};
    float rsm[4][4];
#pragma unroll
    for (int mi = 0; mi < 4; ++mi)
#pragma unroll
        for (int r = 0; r < 4; ++r) rsm[mi][r] = 0.f;

#pragma unroll
    for (int mi = 0; mi < 4; ++mi) {
#pragma unroll
        for (int ni = 0; ni < 4; ++ni) {
#pragma unroll
            for (int r = 0; r < 4; ++r) {
                float e = __expf(acc[mi][ni][r] * 0.0625f - 32.0f);
                csum[ni] += e;
                rsm[mi][r] += e;
            }
        }
    }
#pragma unroll
    for (int ni = 0; ni < 4; ++ni) {
        float s = csum[ni];
        s += __shfl_xor(s, 16);
        s += __shfl_xor(s, 32);
        if ((lane >> 4) == 0)
            atomicAdd(&rsum[b * Nc + col0 + wn * 64 + ni * 16 + lane], s);
    }
    if (i != j) {
#pragma unroll
        for (int mi = 0; mi < 4; ++mi) {
#pragma unroll
            for (int r = 0; r < 4; ++r) {
                float s = rsm[mi][r];
                s += __shfl_xor(s, 1);
                s += __shfl_xor(s, 2);
                s += __shfl_xor(s, 4);
                s += __shfl_xor(s, 8);
                if ((lane & 15) == 0)
                    atomicAdd(&rsum[b * Nc + row0 + wm * 64 + mi * 16 + ((lane >> 4) << 2) + r], s);
            }
        }
    }
}

__global__ __launch_bounds__(256) void gemm2_write_sym(
    const unsigned short* __restrict__ F, const float* __restrict__ invr,
    const int* __restrict__ mask, float* __restrict__ out) {
    __shared__ unsigned short As[BM * BK];
    __shared__ unsigned short Bs[BN * BK];
    __shared__ float Ts[32 * 132];
    const int tid = threadIdx.x;
    const int lane = tid & 63;
    const int wave = tid >> 6;
    const int wm = wave >> 1, wn = wave & 1;
    const int l15 = lane & 15, q = lane >> 4;
    const int b = blockIdx.y;

    int idx = blockIdx.x;
    int j = 0;
    while (((j + 1) * (j + 2) / 2) <= idx) ++j;
    int i = idx - j * (j + 1) / 2;
    const int row0 = i * BM;
    const int col0 = j * BN;
    const unsigned short* Fb = F + (size_t)b * Nc * PH;

    f32x4 acc[4][4] = {};

    for (int k0 = 0; k0 < PH; k0 += BK) {
#pragma unroll
        for (int jj = 0; jj < 2; ++jj) {
            int e = jj * 256 + tid;
            int rr = e >> 2, cc = e & 3;
            load16_lds(&Fb[(size_t)(row0 + rr) * PH + k0 + cc * 8], &As[e * 8]);
            load16_lds(&Fb[(size_t)(col0 + rr) * PH + k0 + cc * 8], &Bs[e * 8]);
        }
        __syncthreads();

        bf16x8 af[4], bfr[4];
#pragma unroll
        for (int qq = 0; qq < 4; ++qq) {
            af[qq]  = *(const bf16x8*)&As[(wm * 64 + qq * 16 + l15) * BK + q * 8];
            bfr[qq] = *(const bf16x8*)&Bs[(wn * 64 + qq * 16 + l15) * BK + q * 8];
        }
#pragma unroll
        for (int mi = 0; mi < 4; ++mi)
#pragma unroll
            for (int ni = 0; ni < 4; ++ni)
                acc[mi][ni] = __builtin_amdgcn_mfma_f32_16x16x32_bf16(af[mi], bfr[ni], acc[mi][ni], 0, 0, 0);
        __syncthreads();
    }

#pragma unroll
    for (int mi = 0; mi < 4; ++mi)
#pragma unroll
        for (int ni = 0; ni < 4; ++ni)
#pragma unroll
            for (int r = 0; r < 4; ++r)
                acc[mi][ni][r] = __expf(acc[mi][ni][r] * 0.0625f - 32.0f);

    float* outb = out + (size_t)b * NN;

    float iv[4];
#pragma unroll
    for (int ni = 0; ni < 4; ++ni)
        iv[ni] = invr[b * Nc + col0 + wn * 64 + ni * 16 + l15];
#pragma unroll
    for (int mi = 0; mi < 4; ++mi) {
        int rowb = row0 + wm * 64 + mi * 16 + (q << 2);
        const int4 mr4 = *(const int4*)&mask[b * Nc + rowb];
        float mr[4] = {(float)mr4.x, (float)mr4.y, (float)mr4.z, (float)mr4.w};
#pragma unroll
        for (int ni = 0; ni < 4; ++ni) {
            int col = col0 + wn * 64 + ni * 16 + l15;
#pragma unroll
            for (int r = 0; r < 4; ++r)
                outb[(size_t)(rowb + r) * Nc + col] = acc[mi][ni][r] * iv[ni] * mr[r];
        }
    }

    if (i != j) {
#pragma unroll
        for (int ci = 0; ci < 4; ++ci) {
            __syncthreads();
            if (wn == (ci >> 1)) {
#pragma unroll
                for (int ni2 = 0; ni2 < 2; ++ni2) {
                    int ni = (ci & 1) * 2 + ni2;
#pragma unroll
                    for (int mi = 0; mi < 4; ++mi) {
                        *(float4*)&Ts[(ni2 * 16 + l15) * 132 + wm * 64 + mi * 16 + (q << 2)] =
                            *(float4*)&acc[mi][ni];
                    }
                }
            }
            __syncthreads();
            int cl = tid >> 3;
            int f0 = tid & 7;
            int nn = col0 + ci * 32 + cl;
            float mrow = (float)mask[b * Nc + nn];
            float* orow = &outb[(size_t)nn * Nc + row0];
#pragma unroll
            for (int g = 0; g < 4; ++g) {
                int f = f0 + g * 8;
                float4 ev  = *(float4*)&Ts[cl * 132 + 4 * f];
                float4 iv4 = *(const float4*)&invr[b * Nc + row0 + 4 * f];
                float4 o;
                o.x = ev.x * iv4.x * mrow;
                o.y = ev.y * iv4.y * mrow;
                o.z = ev.z * iv4.z * mrow;
                o.w = ev.w * iv4.w * mrow;
                *(float4*)&orow[4 * f] = o;
            }
        }
    }
}

// ---------------------------------------------------------------------------
extern "C" void kernel_launch(void* const* d_in, const int* in_sizes, int n_in,
                              void* d_out, int out_size, void* d_ws, size_t ws_size,
                              hipStream_t stream) {
    const float* ctx  = (const float*)d_in[0];   // [8,2048,512] fp32
    const float* W    = (const float*)d_in[1];   // [16,32,512] fp32
    const int*   mask = (const int*)d_in[2];     // [8,2048] int32
    float* out = (float*)d_out;                  // [8,2048,2048] fp32

    char* ws = (char*)d_ws;

    // Layout (fp16 Ework): 1088 tiles * 32KB = 35651584 B, overlays dead Xb/Wb.
    //   [0 .. 35651584)           Ework fp16   (Xb at 0, Wb at 16777216)
    //   [35651584 .. 52428800)    F (bf16, 16384x512)
    //   [52428800 .. 52494336)    rsum
    //   [52494336 .. 52559872)    invr
    //   [52559872 .. 52625408)    hd  (h[r] = ||F_r||^2/32)
    //   [52625408 .. 52690944)    pH  (exp(h[r]))
    const size_t NEED = 52690944;

    if (ws_size >= NEED) {
        unsigned short* Ework = (unsigned short*)ws;
        unsigned short* Xb    = (unsigned short*)ws;
        unsigned short* Wb    = (unsigned short*)(ws + 16777216);
        unsigned short* F     = (unsigned short*)(ws + 35651584);
        float*          rsum  = (float*)(ws + 52428800);
        float*          invr  = (float*)(ws + 52494336);
        float*          hd    = (float*)(ws + 52559872);
        float*          pH    = (float*)(ws + 52625408);

        prep_kernel<<<8192, 256, 0, stream>>>(ctx, W, Xb, Wb, rsum);
        gemm1_relu<<<dim3(4, 128), 256, 0, stream>>>(Xb, Wb, F);
        diag_kernel<<<4096, 256, 0, stream>>>(F, hd, pH);
        gemm2_store<<<1088, 256, 0, stream>>>(F, hd, pH, rsum, Ework);
        invr_kernel<<<64, 256, 0, stream>>>(rsum, mask, invr);
        scatter_out<<<1088, 256, 0, stream>>>(Ework, invr, pH, mask, out);
    } else {
        // fallback: original recompute path (needs ~34.2 MB)
        unsigned short* Xb = (unsigned short*)ws;
        unsigned short* Wb = (unsigned short*)(ws + 16777216);
        unsigned short* F  = (unsigned short*)(ws + 16777216 + 524288);
        float* rsum        = (float*)(ws + 16777216 + 524288 + 16777216);
        float* invr        = (float*)(ws + 16777216 + 524288 + 16777216 + 65536);

        prep_kernel<<<8192, 256, 0, stream>>>(ctx, W, Xb, Wb, rsum);
        gemm1_relu<<<dim3(4, 128), 256, 0, stream>>>(Xb, Wb, F);
        gemm2_rsum<<<dim3(136, 8), 256, 0, stream>>>(F, rsum);
        invr_kernel<<<64, 256, 0, stream>>>(rsum, mask, invr);
        gemm2_write_sym<<<dim3(136, 8), 256, 0, stream>>>(F, invr, mask, out);
    }
}

// Round 5
// 229.895 us; speedup vs baseline: 1.0934x; 1.0705x over previous
//
#include <hip/hip_runtime.h>

// Problem constants
#define Bc 8
#define Nc 2048
#define Dc 512
#define PH 512            // P*H
#define NN 4194304        // N*N
#define NT 136            // upper-tri 128x128 tiles: 16*17/2

#define BM 128
#define BN 128
#define BK 32

typedef __attribute__((ext_vector_type(8))) short bf16x8;
typedef __attribute__((ext_vector_type(4))) float f32x4;

static __device__ __forceinline__ unsigned short f2b(float x) {
    union { float f; unsigned u; } v; v.f = x;
    unsigned r = v.u + 0x7fffu + ((v.u >> 16) & 1u);   // RNE to bf16
    return (unsigned short)(r >> 16);
}

static __device__ __forceinline__ float b2f(unsigned short x) {
    return __builtin_bit_cast(float, (unsigned)x << 16);
}

// async global->LDS DMA, 16 bytes per lane; LDS dest = wave-uniform base + lane*16
static __device__ __forceinline__ void load16_lds(const unsigned short* g, unsigned short* l) {
    __builtin_amdgcn_global_load_lds(
        (const __attribute__((address_space(1))) void*)g,
        (__attribute__((address_space(3))) void*)l,
        16, 0, 0);
}

// ---------------------------------------------------------------------------
// prep: context fp32 -> bf16, W fp32 -> bf16, zero rsum
// ---------------------------------------------------------------------------
__global__ __launch_bounds__(256) void prep_kernel(
    const float* __restrict__ ctx, const float* __restrict__ W,
    unsigned short* __restrict__ Xb, unsigned short* __restrict__ Wb,
    float* __restrict__ rsum) {
    int t = blockIdx.x * 256 + threadIdx.x;
    if (t < 2097152) {
        float4 v = ((const float4*)ctx)[t];
        ushort4 o;
        o.x = f2b(v.x); o.y = f2b(v.y); o.z = f2b(v.z); o.w = f2b(v.w);
        ((ushort4*)Xb)[t] = o;
    }
    if (t < 65536) {
        float4 v = ((const float4*)W)[t];
        ushort4 o;
        o.x = f2b(v.x); o.y = f2b(v.y); o.z = f2b(v.z); o.w = f2b(v.w);
        ((ushort4*)Wb)[t] = o;
    }
    if (t < 4096) {
        float4 z; z.x = 0.f; z.y = 0.f; z.z = 0.f; z.w = 0.f;
        ((float4*)rsum)[t] = z;
    }
}

// ---------------------------------------------------------------------------
// GEMM1: F = relu(Xb @ Wb^T)   Xb:[16384,512] Wb:[512,512]
// grid: 512 1-D with XCD swizzle: the 4 col-blocks of one A-row-panel land on
// ONE XCD (bids {x, x+8, x+16, x+24} share XCD x under round-robin), so the
// 131 KB A-panel is fetched once per XCD instead of 4x across XCDs.
// ---------------------------------------------------------------------------
__global__ __launch_bounds__(256) void gemm1_relu(
    const unsigned short* __restrict__ Xb, const unsigned short* __restrict__ Wb,
    unsigned short* __restrict__ F) {
    __shared__ unsigned short As[BM * BK];
    __shared__ unsigned short Bs[BN * BK];
    const int tid = threadIdx.x;
    const int lane = tid & 63;
    const int wave = tid >> 6;
    const int wm = wave >> 1, wn = wave & 1;
    const int bid = blockIdx.x;
    const int row0 = ((bid & 7) + ((bid >> 5) << 3)) * BM;   // y = (bid&7)+8*(bid>>5)
    const int col0 = ((bid >> 3) & 3) * BN;                  // c = (bid>>3)&3

    f32x4 acc[4][4] = {};

    for (int k0 = 0; k0 < Dc; k0 += BK) {
#pragma unroll
        for (int j = 0; j < 2; ++j) {
            int e = j * 256 + tid;
            int rr = e >> 2, cc = e & 3;
            load16_lds(&Xb[(size_t)(row0 + rr) * Dc + k0 + cc * 8], &As[e * 8]);
            load16_lds(&Wb[(size_t)(col0 + rr) * Dc + k0 + cc * 8], &Bs[e * 8]);
        }
        __syncthreads();

        bf16x8 af[4], bfr[4];
#pragma unroll
        for (int i = 0; i < 4; ++i) {
            af[i]  = *(const bf16x8*)&As[(wm * 64 + i * 16 + (lane & 15)) * BK + (lane >> 4) * 8];
            bfr[i] = *(const bf16x8*)&Bs[(wn * 64 + i * 16 + (lane & 15)) * BK + (lane >> 4) * 8];
        }
#pragma unroll
        for (int mi = 0; mi < 4; ++mi)
#pragma unroll
            for (int ni = 0; ni < 4; ++ni)
                acc[mi][ni] = __builtin_amdgcn_mfma_f32_16x16x32_bf16(af[mi], bfr[ni], acc[mi][ni], 0, 0, 0);
        __syncthreads();
    }

#pragma unroll
    for (int mi = 0; mi < 4; ++mi) {
#pragma unroll
        for (int ni = 0; ni < 4; ++ni) {
            int col  = col0 + wn * 64 + ni * 16 + (lane & 15);
            int rowb = row0 + wm * 64 + mi * 16 + ((lane >> 4) << 2);
#pragma unroll
            for (int r = 0; r < 4; ++r) {
                float v = fmaxf(acc[mi][ni][r], 0.0f);
                F[(size_t)(rowb + r) * PH + col] = f2b(v);
            }
        }
    }
}

// ---------------------------------------------------------------------------
// pass 3: tri-GEMM, e = exp(S/16-32) stored BF16 (full fp32 exponent range:
// no under/overflow, rel err 2^-9), rsum (fp32, exact e) atomics.
// grid: 1088 1-D (b = blk&7 -> batch==XCD affinity), block 256.
// ---------------------------------------------------------------------------
__global__ __launch_bounds__(256) void gemm2_store(
    const unsigned short* __restrict__ F, float* __restrict__ rsum,
    unsigned short* __restrict__ Ework) {
    __shared__ unsigned short As[BM * BK];
    __shared__ unsigned short Bs[BN * BK];
    const int tid = threadIdx.x;
    const int lane = tid & 63;
    const int wave = tid >> 6;
    const int wm = wave >> 1, wn = wave & 1;
    const int l15 = lane & 15, q = lane >> 4;
    const int b = blockIdx.x & 7;          // batch -> XCD (L2 locality heuristic)
    const int idx = blockIdx.x >> 3;

    // upper-triangular tile index: idx = j*(j+1)/2 + i, i <= j
    int j = 0;
    while (((j + 1) * (j + 2) / 2) <= idx) ++j;
    int i = idx - j * (j + 1) / 2;
    const int row0 = i * BM;
    const int col0 = j * BN;
    const unsigned short* Fb = F + (size_t)b * Nc * PH;

    f32x4 acc[4][4] = {};

    for (int k0 = 0; k0 < PH; k0 += BK) {
#pragma unroll
        for (int jj = 0; jj < 2; ++jj) {
            int e = jj * 256 + tid;
            int rr = e >> 2, cc = e & 3;
            load16_lds(&Fb[(size_t)(row0 + rr) * PH + k0 + cc * 8], &As[e * 8]);
            load16_lds(&Fb[(size_t)(col0 + rr) * PH + k0 + cc * 8], &Bs[e * 8]);
        }
        __syncthreads();

        bf16x8 af[4], bfr[4];
#pragma unroll
        for (int qq = 0; qq < 4; ++qq) {
            af[qq]  = *(const bf16x8*)&As[(wm * 64 + qq * 16 + l15) * BK + q * 8];
            bfr[qq] = *(const bf16x8*)&Bs[(wn * 64 + qq * 16 + l15) * BK + q * 8];
        }
#pragma unroll
        for (int mi = 0; mi < 4; ++mi)
#pragma unroll
            for (int ni = 0; ni < 4; ++ni)
                acc[mi][ni] = __builtin_amdgcn_mfma_f32_16x16x32_bf16(af[mi], bfr[ni], acc[mi][ni], 0, 0, 0);
        __syncthreads();
    }

    // epilogue: e = exp(S/16-32); store tile bf16; accumulate fp32 sums
    unsigned short* Et = Ework + (size_t)(b * NT + idx) * 16384;

    float csum[4] = {0.f, 0.f, 0.f, 0.f};
    float rsm[4][4];
#pragma unroll
    for (int mi = 0; mi < 4; ++mi)
#pragma unroll
        for (int r = 0; r < 4; ++r) rsm[mi][r] = 0.f;

#pragma unroll
    for (int mi = 0; mi < 4; ++mi) {
#pragma unroll
        for (int ni = 0; ni < 4; ++ni) {
#pragma unroll
            for (int r = 0; r < 4; ++r) {
                float e = __expf(acc[mi][ni][r] * 0.0625f - 32.0f);
                Et[(wm * 64 + mi * 16 + (q << 2) + r) * 128 + wn * 64 + ni * 16 + l15] = f2b(e);
                csum[ni] += e;
                rsm[mi][r] += e;
            }
        }
    }
#pragma unroll
    for (int ni = 0; ni < 4; ++ni) {
        float s = csum[ni];
        s += __shfl_xor(s, 16);
        s += __shfl_xor(s, 32);
        if ((lane >> 4) == 0)
            atomicAdd(&rsum[b * Nc + col0 + wn * 64 + ni * 16 + lane], s);
    }
    if (i != j) {
#pragma unroll
        for (int mi = 0; mi < 4; ++mi) {
#pragma unroll
            for (int r = 0; r < 4; ++r) {
                float s = rsm[mi][r];
                s += __shfl_xor(s, 1);
                s += __shfl_xor(s, 2);
                s += __shfl_xor(s, 4);
                s += __shfl_xor(s, 8);
                if ((lane & 15) == 0)
                    atomicAdd(&rsum[b * Nc + row0 + wm * 64 + mi * 16 + ((lane >> 4) << 2) + r], s);
            }
        }
    }
}

// ---------------------------------------------------------------------------
// pass 4 (final): pure memory-bound scatter, bf16 e-tiles, inline invr.
// Per block: compute invr = mask/rsum for its 128 cols + 128 rows into LDS
// (rsum complete after gemm2_store; kernel boundary = full visibility), then
// read 32 KB bf16 tile coalesced, write original orientation directly, write
// mirror (i != j) via padded LDS transpose. grid 1088, block 256.
// ---------------------------------------------------------------------------
__global__ __launch_bounds__(256) void scatter_out(
    const unsigned short* __restrict__ Ework, const float* __restrict__ rsum,
    const int* __restrict__ mask, float* __restrict__ out) {
    __shared__ float Ts[32 * 132];
    __shared__ float invA[128];   // invr for cols col0..col0+127 (m-axis)
    __shared__ float invB[128];   // invr for rows row0..row0+127 (mirror m-axis)
    const int tid = threadIdx.x;
    const int b = blockIdx.x & 7;
    const int idx = blockIdx.x >> 3;

    int j = 0;
    while (((j + 1) * (j + 2) / 2) <= idx) ++j;
    int i = idx - j * (j + 1) / 2;
    const int row0 = i * BM;   // n-range of stored tile rows
    const int col0 = j * BN;   // m-range of stored tile cols

    const unsigned short* Et = Ework + (size_t)(b * NT + idx) * 16384;
    const float* rsb  = rsum + b * Nc;
    const int*   mb   = mask + b * Nc;
    float* outb = out + (size_t)b * NN;

    // inline invr (one value per thread)
    if (tid < 128)       invA[tid]       = (float)mb[col0 + tid]       / rsb[col0 + tid];
    else                 invB[tid - 128] = (float)mb[row0 + tid - 128] / rsb[row0 + tid - 128];
    __syncthreads();

    const int cl = tid >> 3, f0 = tid & 7;   // phase A: 32 rows x 8 lanes/row
    const int mc = tid >> 1, h  = tid & 1;   // phase B: 128 mirror-rows x 2 halves

    for (int ci = 0; ci < 4; ++ci) {         // 32-row chunks of the 128x128 tile
        if (ci) __syncthreads();             // Ts reuse across chunks
        const int r = ci * 32 + cl;
        const int n = row0 + r;
        const float mrow = (float)mb[n];
#pragma unroll
        for (int g = 0; g < 2; ++g) {        // 2 x 8 bf16 (16B load) per lane
            const int c0 = 64 * g + 8 * f0;
            union { int4 iv; unsigned short hv[8]; } u;
            u.iv = *(const int4*)&Et[r * 128 + c0];
            float ev[8];
#pragma unroll
            for (int k = 0; k < 8; ++k) ev[k] = b2f(u.hv[k]);
            *(float4*)&Ts[cl * 132 + c0]     = *(float4*)&ev[0];
            *(float4*)&Ts[cl * 132 + c0 + 4] = *(float4*)&ev[4];
            float4 iv0 = *(const float4*)&invA[c0];
            float4 iv1 = *(const float4*)&invA[c0 + 4];
            float4 o0, o1;
            o0.x = ev[0] * iv0.x * mrow;
            o0.y = ev[1] * iv0.y * mrow;
            o0.z = ev[2] * iv0.z * mrow;
            o0.w = ev[3] * iv0.w * mrow;
            o1.x = ev[4] * iv1.x * mrow;
            o1.y = ev[5] * iv1.y * mrow;
            o1.z = ev[6] * iv1.z * mrow;
            o1.w = ev[7] * iv1.w * mrow;
            *(float4*)&outb[(size_t)n * Nc + col0 + c0]     = o0;
            *(float4*)&outb[(size_t)n * Nc + col0 + c0 + 4] = o1;
        }
        if (i == j) continue;                // diag tile: no mirror (uniform branch)
        __syncthreads();
        const int a = col0 + mc;             // mirror out-row
        const float mcol = (float)mb[a];
        const int lb0 = ci * 32 + 16 * h;    // offset within invB / Ts rows
        const int nb0 = row0 + lb0;
#pragma unroll
        for (int u = 0; u < 4; ++u) {
            float4 iv = *(const float4*)&invB[lb0 + 4 * u];
            float4 o;
            o.x = Ts[(16 * h + 4 * u + 0) * 132 + mc] * iv.x * mcol;
            o.y = Ts[(16 * h + 4 * u + 1) * 132 + mc] * iv.y * mcol;
            o.z = Ts[(16 * h + 4 * u + 2) * 132 + mc] * iv.z * mcol;
            o.w = Ts[(16 * h + 4 * u + 3) * 132 + mc] * iv.w * mcol;
            *(float4*)&outb[(size_t)a * Nc + nb0 + 4 * u] = o;
        }
    }
}

// ---------------------------------------------------------------------------
// FALLBACK (small workspace): original recompute path, verbatim.
// ---------------------------------------------------------------------------
__global__ __launch_bounds__(256) void invr_kernel(
    const float* __restrict__ rsum, const int* __restrict__ mask,
    float* __restrict__ invr) {
    int t = blockIdx.x * 256 + threadIdx.x;
    if (t < Bc * Nc) invr[t] = (float)mask[t] / rsum[t];
}

__global__ __launch_bounds__(256) void gemm1_relu_fb(
    const unsigned short* __restrict__ Xb, const unsigned short* __restrict__ Wb,
    unsigned short* __restrict__ F) {
    __shared__ unsigned short As[BM * BK];
    __shared__ unsigned short Bs[BN * BK];
    const int tid = threadIdx.x;
    const int lane = tid & 63;
    const int wave = tid >> 6;
    const int wm = wave >> 1, wn = wave & 1;
    const int row0 = blockIdx.y * BM;
    const int col0 = blockIdx.x * BN;

    f32x4 acc[4][4] = {};

    for (int k0 = 0; k0 < Dc; k0 += BK) {
#pragma unroll
        for (int j = 0; j < 2; ++j) {
            int e = j * 256 + tid;
            int rr = e >> 2, cc = e & 3;
            load16_lds(&Xb[(size_t)(row0 + rr) * Dc + k0 + cc * 8], &As[e * 8]);
            load16_lds(&Wb[(size_t)(col0 + rr) * Dc + k0 + cc * 8], &Bs[e * 8]);
        }
        __syncthreads();

        bf16x8 af[4], bfr[4];
#pragma unroll
        for (int i = 0; i < 4; ++i) {
            af[i]  = *(const bf16x8*)&As[(wm * 64 + i * 16 + (lane & 15)) * BK + (lane >> 4) * 8];
            bfr[i] = *(const bf16x8*)&Bs[(wn * 64 + i * 16 + (lane & 15)) * BK + (lane >> 4) * 8];
        }
#pragma unroll
        for (int mi = 0; mi < 4; ++mi)
#pragma unroll
            for (int ni = 0; ni < 4; ++ni)
                acc[mi][ni] = __builtin_amdgcn_mfma_f32_16x16x32_bf16(af[mi], bfr[ni], acc[mi][ni], 0, 0, 0);
        __syncthreads();
    }

#pragma unroll
    for (int mi = 0; mi < 4; ++mi) {
#pragma unroll
        for (int ni = 0; ni < 4; ++ni) {
            int col  = col0 + wn * 64 + ni * 16 + (lane & 15);
            int rowb = row0 + wm * 64 + mi * 16 + ((lane >> 4) << 2);
#pragma unroll
            for (int r = 0; r < 4; ++r) {
                float v = fmaxf(acc[mi][ni][r], 0.0f);
                F[(size_t)(rowb + r) * PH + col] = f2b(v);
            }
        }
    }
}

__global__ __launch_bounds__(256) void gemm2_rsum(
    const unsigned short* __restrict__ F, float* __restrict__ rsum) {
    __shared__ unsigned short As[BM * BK];
    __shared__ unsigned short Bs[BN * BK];
    const int tid = threadIdx.x;
    const int lane = tid & 63;
    const int wave = tid >> 6;
    const int wm = wave >> 1, wn = wave & 1;
    const int b = blockIdx.y;

    int idx = blockIdx.x;
    int j = 0;
    while (((j + 1) * (j + 2) / 2) <= idx) ++j;
    int i = idx - j * (j + 1) / 2;
    const int row0 = i * BM;
    const int col0 = j * BN;
    const unsigned short* Fb = F + (size_t)b * Nc * PH;

    f32x4 acc[4][4] = {};

    for (int k0 = 0; k0 < PH; k0 += BK) {
#pragma unroll
        for (int jj = 0; jj < 2; ++jj) {
            int e = jj * 256 + tid;
            int rr = e >> 2, cc = e & 3;
            load16_lds(&Fb[(size_t)(row0 + rr) * PH + k0 + cc * 8], &As[e * 8]);
            load16_lds(&Fb[(size_t)(col0 + rr) * PH + k0 + cc * 8], &Bs[e * 8]);
        }
        __syncthreads();

        bf16x8 af[4], bfr[4];
#pragma unroll
        for (int q = 0; q < 4; ++q) {
            af[q]  = *(const bf16x8*)&As[(wm * 64 + q * 16 + (lane & 15)) * BK + (lane >> 4) * 8];
            bfr[q] = *(const bf16x8*)&Bs[(wn * 64 + q * 16 + (lane & 15)) * BK + (lane >> 4) * 8];
        }
#pragma unroll
        for (int mi = 0; mi < 4; ++mi)
#pragma unroll
            for (int ni = 0; ni < 4; ++ni)
                acc[mi][ni] = __builtin_amdgcn_mfma_f32_16x16x32_bf16(af[mi], bfr[ni], acc[mi][ni], 0, 0, 0);
        __syncthreads();
    }

    float csum[4] = {0.f, 0.f, 0.f, 0.f};
    float rsm[4][4];
#pragma unroll
    for (int mi = 0; mi < 4; ++mi)
#pragma unroll
        for (int r = 0; r < 4; ++r) rsm[mi][r] = 0.f;

#pragma unroll
    for (int mi = 0; mi < 4; ++mi) {
#pragma unroll
        for (int ni = 0; ni < 4; ++ni) {
#pragma unroll
            for (int r = 0; r < 4; ++r) {
                float e = __expf(acc[mi][ni][r] * 0.0625f - 32.0f);
                csum[ni] += e;
                rsm[mi][r] += e;
            }
        }
    }
#pragma unroll
    for (int ni = 0; ni < 4; ++ni) {
        float s = csum[ni];
        s += __shfl_xor(s, 16);
        s += __shfl_xor(s, 32);
        if ((lane >> 4) == 0)
            atomicAdd(&rsum[b * Nc + col0 + wn * 64 + ni * 16 + lane], s);
    }
    if (i != j) {
#pragma unroll
        for (int mi = 0; mi < 4; ++mi) {
#pragma unroll
            for (int r = 0; r < 4; ++r) {
                float s = rsm[mi][r];
                s += __shfl_xor(s, 1);
                s += __shfl_xor(s, 2);
                s += __shfl_xor(s, 4);
                s += __shfl_xor(s, 8);
                if ((lane & 15) == 0)
                    atomicAdd(&rsum[b * Nc + row0 + wm * 64 + mi * 16 + ((lane >> 4) << 2) + r], s);
            }
        }
    }
}

__global__ __launch_bounds__(256) void gemm2_write_sym(
    const unsigned short* __restrict__ F, const float* __restrict__ invr,
    const int* __restrict__ mask, float* __restrict__ out) {
    __shared__ unsigned short As[BM * BK];
    __shared__ unsigned short Bs[BN * BK];
    __shared__ float Ts[32 * 132];
    const int tid = threadIdx.x;
    const int lane = tid & 63;
    const int wave = tid >> 6;
    const int wm = wave >> 1, wn = wave & 1;
    const int l15 = lane & 15, q = lane >> 4;
    const int b = blockIdx.y;

    int idx = blockIdx.x;
    int j = 0;
    while (((j + 1) * (j + 2) / 2) <= idx) ++j;
    int i = idx - j * (j + 1) / 2;
    const int row0 = i * BM;
    const int col0 = j * BN;
    const unsigned short* Fb = F + (size_t)b * Nc * PH;

    f32x4 acc[4][4] = {};

    for (int k0 = 0; k0 < PH; k0 += BK) {
#pragma unroll
        for (int jj = 0; jj < 2; ++jj) {
            int e = jj * 256 + tid;
            int rr = e >> 2, cc = e & 3;
            load16_lds(&Fb[(size_t)(row0 + rr) * PH + k0 + cc * 8], &As[e * 8]);
            load16_lds(&Fb[(size_t)(col0 + rr) * PH + k0 + cc * 8], &Bs[e * 8]);
        }
        __syncthreads();

        bf16x8 af[4], bfr[4];
#pragma unroll
        for (int qq = 0; qq < 4; ++qq) {
            af[qq]  = *(const bf16x8*)&As[(wm * 64 + qq * 16 + l15) * BK + q * 8];
            bfr[qq] = *(const bf16x8*)&Bs[(wn * 64 + qq * 16 + l15) * BK + q * 8];
        }
#pragma unroll
        for (int mi = 0; mi < 4; ++mi)
#pragma unroll
            for (int ni = 0; ni < 4; ++ni)
                acc[mi][ni] = __builtin_amdgcn_mfma_f32_16x16x32_bf16(af[mi], bfr[ni], acc[mi][ni], 0, 0, 0);
        __syncthreads();
    }

#pragma unroll
    for (int mi = 0; mi < 4; ++mi)
#pragma unroll
        for (int ni = 0; ni < 4; ++ni)
#pragma unroll
            for (int r = 0; r < 4; ++r)
                acc[mi][ni][r] = __expf(acc[mi][ni][r] * 0.0625f - 32.0f);

    float* outb = out + (size_t)b * NN;

    float iv[4];
#pragma unroll
    for (int ni = 0; ni < 4; ++ni)
        iv[ni] = invr[b * Nc + col0 + wn * 64 + ni * 16 + l15];
#pragma unroll
    for (int mi = 0; mi < 4; ++mi) {
        int rowb = row0 + wm * 64 + mi * 16 + (q << 2);
        const int4 mr4 = *(const int4*)&mask[b * Nc + rowb];
        float mr[4] = {(float)mr4.x, (float)mr4.y, (float)mr4.z, (float)mr4.w};
#pragma unroll
        for (int ni = 0; ni < 4; ++ni) {
            int col = col0 + wn * 64 + ni * 16 + l15;
#pragma unroll
            for (int r = 0; r < 4; ++r)
                outb[(size_t)(rowb + r) * Nc + col] = acc[mi][ni][r] * iv[ni] * mr[r];
        }
    }

    if (i != j) {
#pragma unroll
        for (int ci = 0; ci < 4; ++ci) {
            __syncthreads();
            if (wn == (ci >> 1)) {
#pragma unroll
                for (int ni2 = 0; ni2 < 2; ++ni2) {
                    int ni = (ci & 1) * 2 + ni2;
#pragma unroll
                    for (int mi = 0; mi < 4; ++mi) {
                        *(float4*)&Ts[(ni2 * 16 + l15) * 132 + wm * 64 + mi * 16 + (q << 2)] =
                            *(float4*)&acc[mi][ni];
                    }
                }
            }
            __syncthreads();
            int cl = tid >> 3;
            int f0 = tid & 7;
            int nn = col0 + ci * 32 + cl;
            float mrow = (float)mask[b * Nc + nn];
            float* orow = &outb[(size_t)nn * Nc + row0];
#pragma unroll
            for (int g = 0; g < 4; ++g) {
                int f = f0 + g * 8;
                float4 ev  = *(float4*)&Ts[cl * 132 + 4 * f];
                float4 iv4 = *(const float4*)&invr[b * Nc + row0 + 4 * f];
                float4 o;
                o.x = ev.x * iv4.x * mrow;
                o.y = ev.y * iv4.y * mrow;
                o.z = ev.z * iv4.z * mrow;
                o.w = ev.w * iv4.w * mrow;
                *(float4*)&orow[4 * f] = o;
            }
        }
    }
}

// ---------------------------------------------------------------------------
extern "C" void kernel_launch(void* const* d_in, const int* in_sizes, int n_in,
                              void* d_out, int out_size, void* d_ws, size_t ws_size,
                              hipStream_t stream) {
    const float* ctx  = (const float*)d_in[0];   // [8,2048,512] fp32
    const float* W    = (const float*)d_in[1];   // [16,32,512] fp32
    const int*   mask = (const int*)d_in[2];     // [8,2048] int32
    float* out = (float*)d_out;                  // [8,2048,2048] fp32

    char* ws = (char*)d_ws;

    // Layout (bf16 Ework): 1088 tiles * 32KB = 35651584 B, overlays dead Xb/Wb.
    //   [0 .. 35651584)           Ework bf16   (Xb at 0, Wb at 16777216)
    //   [35651584 .. 52428800)    F (bf16, 16384x512)
    //   [52428800 .. 52494336)    rsum
    const size_t NEED = 52494336;

    if (ws_size >= NEED) {
        unsigned short* Ework = (unsigned short*)ws;
        unsigned short* Xb    = (unsigned short*)ws;
        unsigned short* Wb    = (unsigned short*)(ws + 16777216);
        unsigned short* F     = (unsigned short*)(ws + 35651584);
        float*          rsum  = (float*)(ws + 52428800);

        prep_kernel<<<8192, 256, 0, stream>>>(ctx, W, Xb, Wb, rsum);
        gemm1_relu<<<512, 256, 0, stream>>>(Xb, Wb, F);
        gemm2_store<<<1088, 256, 0, stream>>>(F, rsum, Ework);      // tri-GEMM + bf16 e-store + rsum
        scatter_out<<<1088, 256, 0, stream>>>(Ework, rsum, mask, out);  // inline invr + pure-BW pass
    } else {
        // fallback: original recompute path (needs ~34.2 MB)
        unsigned short* Xb = (unsigned short*)ws;
        unsigned short* Wb = (unsigned short*)(ws + 16777216);
        unsigned short* F  = (unsigned short*)(ws + 16777216 + 524288);
        float* rsum        = (float*)(ws + 16777216 + 524288 + 16777216);
        float* invr        = (float*)(ws + 16777216 + 524288 + 16777216 + 65536);

        prep_kernel<<<8192, 256, 0, stream>>>(ctx, W, Xb, Wb, rsum);
        gemm1_relu_fb<<<dim3(4, 128), 256, 0, stream>>>(Xb, Wb, F);
        gemm2_rsum<<<dim3(136, 8), 256, 0, stream>>>(F, rsum);
        invr_kernel<<<64, 256, 0, stream>>>(rsum, mask, invr);
        gemm2_write_sym<<<dim3(136, 8), 256, 0, stream>>>(F, invr, mask, out);
    }
}